// Round 2
// baseline (1294.417 us; speedup 1.0000x reference)
//
#include <hip/hip_runtime.h>
#include <hip/hip_bf16.h>

#define TT 128
#define BATCH 64
#define WCH 16
#define CEMB 32
#define CCH 128
#define HID 512
#define GATES 2048
#define INF_ 428
#define KP 448
#define NOUT 20

typedef float f32x4 __attribute__((ext_vector_type(4)));
typedef __bf16 b8v __attribute__((ext_vector_type(8)));
typedef __hip_bfloat16 bf16;

__device__ __forceinline__ float sigm(float x){ return 1.f/(1.f+__expf(-x)); }
__device__ __forceinline__ float tanh_(float x){ float e=__expf(2.f*x); return (e-1.f)/(e+1.f); }

// ---------------- feat build: word emb + char conv+maxpool, bf16, K padded to 448
__global__ void k_feat(const int* __restrict__ words, const int* __restrict__ chars,
                       const float* __restrict__ embW, const float* __restrict__ cembW,
                       const float* __restrict__ convW, const float* __restrict__ convb,
                       bf16* __restrict__ featb) {
  int r = blockIdx.x;            // r = t*64 + b
  int t = r >> 6, b = r & 63;
  int tid = threadIdx.x;         // 128 threads
  int wi = words[t*BATCH + b];
  const float* src = embW + (size_t)wi * 300;
  bf16* dst = featb + (size_t)r * KP;
  for (int k = tid; k < 300; k += 128) dst[k] = __float2bfloat16(src[k]);
  if (tid < KP - INF_) dst[INF_ + tid] = __float2bfloat16(0.f);
  // char conv: one output channel per thread
  int cc = tid, g = cc >> 2;
  const int* ch = chars + ((size_t)b*TT + t)*WCH;
  float ce[WCH];
  #pragma unroll
  for (int w = 0; w < WCH; ++w) ce[w] = cembW[ch[w]*CEMB + g];
  float w0 = convW[cc*3], w1 = convW[cc*3+1], w2 = convW[cc*3+2];
  float m = -1e30f;
  #pragma unroll
  for (int p = 0; p < WCH-2; ++p) m = fmaxf(m, ce[p]*w0 + ce[p+1]*w1 + ce[p+2]*w2);
  dst[300 + cc] = __float2bfloat16(m + convb[cc]);
}

// ---------------- pack weights: gate-permuted rows p = (j>>3)*32 + tau*8 + (j&7)
__global__ void k_pack(const float* __restrict__ WihF, const float* __restrict__ WhhF,
                       const float* __restrict__ bihF, const float* __restrict__ bhhF,
                       const float* __restrict__ WihB, const float* __restrict__ WhhB,
                       const float* __restrict__ bihB, const float* __restrict__ bhhB,
                       bf16* __restrict__ Wihp, bf16* __restrict__ Whhp, float* __restrict__ bsum) {
  size_t tid0 = (size_t)blockIdx.x*blockDim.x + threadIdx.x;
  size_t nthr = (size_t)gridDim.x*blockDim.x;
  for (size_t idx = tid0; idx < (size_t)2*GATES*HID; idx += nthr) {
    int k = idx & (HID-1);
    int p = (idx >> 9) & (GATES-1);
    int d = (int)(idx >> 20);
    int j = ((p>>5)<<3) | (p&7);
    int tau = (p>>3)&3;
    const float* Whh = d ? WhhB : WhhF;
    Whhp[idx] = __float2bfloat16(Whh[(size_t)(tau*HID + j)*HID + k]);
  }
  for (size_t idx = tid0; idx < (size_t)2*GATES*KP; idx += nthr) {
    int k = (int)(idx % KP);
    size_t rest = idx / KP;
    int p = (int)(rest & (GATES-1));
    int d = (int)(rest >> 11);
    int j = ((p>>5)<<3) | (p&7);
    int tau = (p>>3)&3;
    const float* Wih = d ? WihB : WihF;
    float v = (k < INF_) ? Wih[(size_t)(tau*HID + j)*INF_ + k] : 0.f;
    Wihp[idx] = __float2bfloat16(v);
  }
  for (size_t idx = tid0; idx < (size_t)2*GATES; idx += nthr) {
    int p = (int)(idx & (GATES-1));
    int d = (int)(idx >> 11);
    int j = ((p>>5)<<3) | (p&7);
    int tau = (p>>3)&3;
    int gg = tau*HID + j;
    bsum[idx] = d ? (bihB[gg]+bhhB[gg]) : (bihF[gg]+bhhF[gg]);
  }
}

// ---------------- input-projection GEMM: M=4096 (permuted gates), N=8192 (t*64+b), K=448
// out xW[t][d][p][b] = bf16( sum_k Wihp[M][k]*featb[N][k] + bsum )
__global__ __launch_bounds__(256) void k_gemm(const bf16* __restrict__ Wihp,
      const bf16* __restrict__ featb, const float* __restrict__ bsum,
      bf16* __restrict__ xW) {
  __shared__ short As[128][72];
  __shared__ short Bs[128][72];
  int m0 = (blockIdx.x & 31) << 7;
  int n0 = (blockIdx.x >> 5) << 7;
  int tid = threadIdx.x;
  int lane = tid & 63;
  int wid = tid >> 6;
  int wr = wid >> 1, wc = wid & 1;
  int lm = lane & 15, kg = lane >> 4;
  f32x4 acc[4][4] = {};
  for (int k0 = 0; k0 < KP; k0 += 64) {
    // stage 128 rows x 64 cols for A and B: 1024 chunks of 8 bf16 each
    #pragma unroll
    for (int c = 0; c < 4; ++c) {
      int ch = tid + c*256;
      int row = ch >> 3, k8 = (ch & 7) << 3;
      *(b8v*)&As[row][k8] = *(const b8v*)&Wihp[(size_t)(m0+row)*KP + k0 + k8];
      *(b8v*)&Bs[row][k8] = *(const b8v*)&featb[(size_t)(n0+row)*KP + k0 + k8];
    }
    __syncthreads();
    #pragma unroll
    for (int ks = 0; ks < 2; ++ks) {
      b8v a[4], bb[4];
      #pragma unroll
      for (int i = 0; i < 4; ++i) a[i]  = *(const b8v*)&As[wr*64 + i*16 + lm][ks*32 + kg*8];
      #pragma unroll
      for (int i = 0; i < 4; ++i) bb[i] = *(const b8v*)&Bs[wc*64 + i*16 + lm][ks*32 + kg*8];
      #pragma unroll
      for (int mi = 0; mi < 4; ++mi)
        #pragma unroll
        for (int ni = 0; ni < 4; ++ni)
          acc[mi][ni] = __builtin_amdgcn_mfma_f32_16x16x32_bf16(a[mi], bb[ni], acc[mi][ni], 0, 0, 0);
    }
    __syncthreads();
  }
  #pragma unroll
  for (int mi = 0; mi < 4; ++mi) {
    #pragma unroll
    for (int ni = 0; ni < 4; ++ni) {
      int r = n0 + wc*64 + ni*16 + lm;
      int t = r >> 6, b = r & 63;
      #pragma unroll
      for (int reg = 0; reg < 4; ++reg) {
        int G = m0 + wr*64 + mi*16 + kg*4 + reg;
        int d = G >> 11, p = G & (GATES-1);
        float v = acc[mi][ni][reg] + bsum[G];
        xW[(((size_t)t*2 + d)*GATES + p)*BATCH + b] = __float2bfloat16(v);
      }
    }
  }
}

// ---------------- one LSTM step, both directions. 512 waves:
// wave = dir(2) x btile(4) x jtile(64). Wave z-tile = 32 permuted gate rows x 16 batch.
__global__ __launch_bounds__(256) void k_step(const bf16* __restrict__ Whhp,
       const bf16* __restrict__ xW, bf16* __restrict__ hs,
       float* __restrict__ cws, int step) {
  int wid = blockIdx.x*4 + (threadIdx.x >> 6);
  int lane = threadIdx.x & 63;
  int dir = wid >> 8;
  int btile = (wid >> 6) & 3;
  int jt = wid & 63;
  int tcur = dir ? (TT-1 - step) : step;
  int b0 = btile << 4, pbase = jt << 5, jbase = jt << 3;
  int col = lane & 15, kg = lane >> 4;
  f32x4 acc0, acc1;
  {
    const bf16* xwp = xW + ((size_t)tcur*2 + dir)*GATES*BATCH;
    #pragma unroll
    for (int reg = 0; reg < 4; ++reg) {
      acc0[reg] = __bfloat162float(xwp[(size_t)(pbase + kg*4 + reg)*BATCH + b0 + col]);
      acc1[reg] = __bfloat162float(xwp[(size_t)(pbase + 16 + kg*4 + reg)*BATCH + b0 + col]);
    }
  }
  if (step > 0) {
    int tprev = dir ? tcur + 1 : tcur - 1;
    const bf16* hp = hs + ((size_t)dir*TT + tprev)*BATCH*HID;
    const bf16* wp = Whhp + (size_t)dir*GATES*HID;
    #pragma unroll
    for (int ks = 0; ks < 16; ++ks) {
      b8v bfrag = *(const b8v*)&hp[(size_t)(b0 + col)*HID + ks*32 + kg*8];
      b8v a0 = *(const b8v*)&wp[(size_t)(pbase + col)*HID + ks*32 + kg*8];
      b8v a1 = *(const b8v*)&wp[(size_t)(pbase + 16 + col)*HID + ks*32 + kg*8];
      acc0 = __builtin_amdgcn_mfma_f32_16x16x32_bf16(a0, bfrag, acc0, 0, 0, 0);
      acc1 = __builtin_amdgcn_mfma_f32_16x16x32_bf16(a1, bfrag, acc1, 0, 0, 0);
    }
  }
  // rows: acc0 = i(j0..7),f(j0..7); acc1 = g(j0..7),o(j0..7). Lane l<32 holds i,g;
  // partner l+32 holds f,o for the SAME j,b -> one xor-32 shuffle.
  f32x4 fsh, osh;
  #pragma unroll
  for (int reg = 0; reg < 4; ++reg) {
    fsh[reg] = __shfl_xor(acc0[reg], 32);
    osh[reg] = __shfl_xor(acc1[reg], 32);
  }
  if (lane < 32) {
    int b = b0 + col;
    float* cp = cws + ((size_t)dir*BATCH + b)*HID + jbase + kg*4;
    bf16* hpw = hs + (((size_t)dir*TT + tcur)*BATCH + b)*HID + jbase + kg*4;
    #pragma unroll
    for (int reg = 0; reg < 4; ++reg) {
      float zi = acc0[reg], zf = fsh[reg], zg = acc1[reg], zo = osh[reg];
      float co = (step > 0) ? cp[reg] : 0.f;
      float cn = sigm(zf)*co + sigm(zi)*tanh_(zg);
      float hv = sigm(zo)*tanh_(cn);
      cp[reg] = cn;
      hpw[reg] = __float2bfloat16(hv);
    }
  }
}

// ---------------- final FC: out[t][b][o] = sum_j hs_f*W + hs_b*W + bias
__global__ void k_fc(const bf16* __restrict__ hs, const float* __restrict__ fcW,
                     const float* __restrict__ fcb, float* __restrict__ out) {
  int t = blockIdx.x;
  for (int item = threadIdx.x; item < BATCH*NOUT; item += blockDim.x) {
    int b = item / NOUT, o = item % NOUT;
    const bf16* hf = hs + ((size_t)t*BATCH + b)*HID;
    const bf16* hb = hs + (((size_t)TT + t)*BATCH + b)*HID;
    const float* w0 = fcW + (size_t)o*2*HID;
    const float* w1 = w0 + HID;
    float s = fcb[o];
    for (int j = 0; j < HID; ++j) s += __bfloat162float(hf[j])*w0[j];
    for (int j = 0; j < HID; ++j) s += __bfloat162float(hb[j])*w1[j];
    out[((size_t)t*BATCH + b)*NOUT + o] = s;
  }
}

extern "C" void kernel_launch(void* const* d_in, const int* in_sizes, int n_in,
                              void* d_out, int out_size, void* d_ws, size_t ws_size,
                              hipStream_t stream) {
  const int* words = (const int*)d_in[0];
  const int* chars = (const int*)d_in[1];
  const float* embW = (const float*)d_in[2];
  const float* cembW = (const float*)d_in[3];
  const float* convW = (const float*)d_in[4];
  const float* convb = (const float*)d_in[5];
  const float* WihF = (const float*)d_in[6];
  const float* WhhF = (const float*)d_in[7];
  const float* bihF = (const float*)d_in[8];
  const float* bhhF = (const float*)d_in[9];
  const float* WihB = (const float*)d_in[10];
  const float* WhhB = (const float*)d_in[11];
  const float* bihB = (const float*)d_in[12];
  const float* bhhB = (const float*)d_in[13];
  const float* fcW = (const float*)d_in[14];
  const float* fcb = (const float*)d_in[15];
  float* out = (float*)d_out;

  char* ws = (char*)d_ws;
  size_t off = 0;
  bf16* xW    = (bf16*)(ws + off); off += (size_t)TT*2*GATES*BATCH*2;  // 64 MiB
  bf16* hsbuf = (bf16*)(ws + off); off += (size_t)2*TT*BATCH*HID*2;    // 16 MiB
  bf16* featb = (bf16*)(ws + off); off += (size_t)TT*BATCH*KP*2;       // 7 MiB
  bf16* Wihp  = (bf16*)(ws + off); off += (size_t)2*GATES*KP*2;        // 3.5 MiB
  bf16* Whhp  = (bf16*)(ws + off); off += (size_t)2*GATES*HID*2;       // 4 MiB
  float* bsum = (float*)(ws + off); off += (size_t)2*GATES*4;
  float* cws  = (float*)(ws + off); off += (size_t)2*BATCH*HID*4;
  if (off > ws_size) return;  // workspace too small -> fail loudly (poison stays)

  k_feat<<<TT*BATCH, 128, 0, stream>>>(words, chars, embW, cembW, convW, convb, featb);
  k_pack<<<2048, 256, 0, stream>>>(WihF, WhhF, bihF, bhhF, WihB, WhhB, bihB, bhhB,
                                   Wihp, Whhp, bsum);
  k_gemm<<<2048, 256, 0, stream>>>(Wihp, featb, bsum, xW);
  for (int s = 0; s < TT; ++s)
    k_step<<<128, 256, 0, stream>>>(Whhp, xW, hsbuf, cws, s);
  k_fc<<<TT, 256, 0, stream>>>(hsbuf, fcW, fcb, out);
}